// Round 13
// baseline (429.133 us; speedup 1.0000x reference)
//
#include <hip/hip_runtime.h>
#include <cstdint>
#include <cstddef>

typedef unsigned int uint;
typedef unsigned short ushort;
typedef __attribute__((ext_vector_type(8))) short bf16x8;
typedef __attribute__((ext_vector_type(4))) float f32x4;

#define CAP 4608   // padded per-bucket capacity (expected 4092, +8 sigma)

__device__ __forceinline__ ushort f2bf(float f) {          // RNE float->bf16
    uint b = __float_as_uint(f);
    return (ushort)((b + 0x7FFF + ((b >> 16) & 1)) >> 16);
}
__device__ __forceinline__ float bf_lo(uint u) { return __uint_as_float(u << 16); }
__device__ __forceinline__ float bf_hi(uint u) { return __uint_as_float(u & 0xFFFF0000u); }

// ============ CSR build, single-pass bucket sort (padded regions) ===========
__global__ __launch_bounds__(256) void k_sort(
        const int* __restrict__ src, const int* __restrict__ dst, int E, int chunk,
        int* __restrict__ bcur, uint* __restrict__ ebuf, int nbkt,
        const float* __restrict__ W1, const float* __restrict__ W2,
        ushort* __restrict__ WT1, ushort* __restrict__ WT2,
        float* __restrict__ sums) {
    __shared__ uint   ebuf_l[8192];
    __shared__ ushort bid_l[8192];
    __shared__ int    sh[256];
    __shared__ int    hist[512], histx[512], cur[512], goff[512];
    const int t   = threadIdx.x;
    const int blk = blockIdx.x;

    // fused weight prep + sums[16][256] zero (independent work)
    {
        int wi = blk * 256 + t;
        if (wi < 16384) {
            int nn = wi >> 7, k = wi & 127;
            WT1[wi] = f2bf(W1[k * 128 + nn]);
        } else if (wi < 32768) {
            int wj = wi - 16384, nn = wj >> 7, k = wj & 127;
            WT2[wj] = f2bf(W2[k * 128 + nn]);
        } else if (wi < 36864) {
            sums[wi - 32768] = 0.f;
        }
    }

    for (int b = t; b < nbkt; b += 256) hist[b] = 0;
    __syncthreads();

    const int beg = blk * chunk;
    const int end = min(beg + chunk, E);
    for (int i = beg + t; i < end; i += 256)
        atomicAdd(&hist[dst[i] >> 8], 1);
    __syncthreads();

    const int b0 = 2 * t, b1 = 2 * t + 1;
    const int c0 = (b0 < nbkt) ? hist[b0] : 0;
    const int c1 = (b1 < nbkt) ? hist[b1] : 0;
    sh[t] = c0 + c1;
    __syncthreads();
    #pragma unroll
    for (int o = 1; o < 256; o <<= 1) {
        int x = (t >= o) ? sh[t - o] : 0;
        __syncthreads();
        sh[t] += x;
        __syncthreads();
    }
    const int ex = sh[t] - (c0 + c1);
    histx[b0] = ex;       histx[b1] = ex + c0;
    cur[b0]   = ex;       cur[b1]   = ex + c0;
    __syncthreads();

    for (int b = t; b < nbkt; b += 256) {
        int h = hist[b];
        int base = (h > 0) ? atomicAdd(&bcur[b], h) : 0;
        goff[b] = b * CAP + base - histx[b];
    }
    __syncthreads();

    for (int i = beg + t; i < end; i += 256) {
        int d = dst[i];
        int s = src[i];
        int b = d >> 8;
        int p = atomicAdd(&cur[b], 1);            // LDS atomic
        ebuf_l[p] = ((uint)(d & 255) << 17) | (uint)s;
        bid_l[p]  = (ushort)b;
    }
    __syncthreads();

    const int cntE = end - beg;
    for (int i = t; i < cntE; i += 256)
        ebuf[goff[bid_l[i]] + i] = ebuf_l[i];
}

// per-bucket fine CSR: fine counts -> dinv, deg, offs(begin), grouped csr
__global__ __launch_bounds__(256) void k_bcsr(
        const uint* __restrict__ ebuf, const int* __restrict__ bcur,
        int n, float* __restrict__ dinv, int* __restrict__ offs,
        int* __restrict__ deg, int* __restrict__ csr) {
    __shared__ int fine[256], finex[256], fcur[256];
    const int b = blockIdx.x;
    const int t = threadIdx.x;
    const int ebeg = b * CAP;
    const int eend = ebeg + bcur[b];
    fine[t] = 0;
    __syncthreads();
    for (int i = ebeg + t; i < eend; i += 256)
        atomicAdd(&fine[ebuf[i] >> 17], 1);
    __syncthreads();
    const int node = b * 256 + t;
    if (node < n) {
        dinv[node] = rsqrtf((float)(fine[t] + 1));
        deg[node]  = fine[t];
    }
    int v = fine[t];
    finex[t] = v;
    __syncthreads();
    #pragma unroll
    for (int o = 1; o < 256; o <<= 1) {
        int x = (t >= o) ? finex[t - o] : 0;
        __syncthreads();
        finex[t] += x;
        __syncthreads();
    }
    const int ex = finex[t] - v;
    fcur[t] = ex;
    if (node < n) offs[node] = ebeg + ex;
    __syncthreads();
    for (int i = ebeg + t; i < eend; i += 256) {
        uint e = ebuf[i];
        int f = (int)(e >> 17);
        int p = atomicAdd(&fcur[f], 1);             // LDS atomic
        csr[ebeg + p] = (int)(e & 0x1FFFF);
    }
}

// ---------------- MFMA GEMM, WT LDS-resident (XOR-swizzled) -----------------
// C[n,128](bf16) = dinv[r] * f(A) @ W.
// LAYER 0: A fp32, f=identity. LAYER 1: A bf16, f=relu(BN(a)); BN params are
// derived in-block from the 8 replicated stat banks (fused bnparam).
template <int LAYER>
__global__ __launch_bounds__(256) void k_gemm(
        const void* __restrict__ Av, const ushort* __restrict__ WT,
        const float* __restrict__ sums, const float* __restrict__ g,
        const float* __restrict__ be, const float* __restrict__ dinv,
        ushort* __restrict__ C, int n, float invn) {
    __shared__ ushort sWT[128 * 128];   // 32 KB, rows XOR-swizzled by (row&7)<<4
    __shared__ float  ssl[256];
    const int tid  = threadIdx.x;
    const int lane = tid & 63;
    const int wid  = tid >> 6;
    const int m0   = blockIdx.x * 64 + wid * 16;
    const int lm   = lane & 15;
    const int lq   = lane >> 4;
    const int row  = m0 + lm;
    const bool rv  = row < n;

    float4 a0f[8];
    uint4  a1u[4];
    if (LAYER == 0) {
        const float* A = (const float*)Av;
        #pragma unroll
        for (int ks = 0; ks < 4; ks++) {
            const int kb = ks * 32 + lq * 8;
            if (rv) {
                a0f[2 * ks]     = *(const float4*)&A[(size_t)row * 128 + kb];
                a0f[2 * ks + 1] = *(const float4*)&A[(size_t)row * 128 + kb + 4];
            } else {
                a0f[2 * ks] = make_float4(0.f, 0.f, 0.f, 0.f);
                a0f[2 * ks + 1] = a0f[2 * ks];
            }
        }
    } else {
        const uint* A = (const uint*)Av;
        #pragma unroll
        for (int ks = 0; ks < 4; ks++) {
            const int kb = ks * 32 + lq * 8;
            a1u[ks] = rv ? *(const uint4*)&A[(size_t)row * 64 + kb / 2]
                         : make_uint4(0, 0, 0, 0);
        }
    }

    {
        const uint4* WT4 = (const uint4*)WT;
        char* sB = (char*)sWT;
        #pragma unroll
        for (int i = 0; i < 8; i++) {
            int idx  = tid + i * 256;
            uint4 v  = WT4[idx];
            int nrow = idx >> 4, j = idx & 15;
            int byte = (nrow * 256 + j * 16) ^ ((nrow & 7) << 4);
            *(uint4*)(sB + byte) = v;
        }
    }
    if (LAYER == 1 && tid < 128) {
        float s = 0.f, s2 = 0.f;
        #pragma unroll
        for (int b = 0; b < 8; b++) {
            s  += sums[b * 256 + tid];
            s2 += sums[b * 256 + 128 + tid];
        }
        float mean = s * invn;
        float var  = s2 * invn - mean * mean;
        float inv  = rsqrtf(var + 1e-5f);
        float sc   = g[tid] * inv;
        ssl[tid]       = sc;
        ssl[128 + tid] = be[tid] - mean * sc;
    }
    __syncthreads();

    f32x4 acc[8];
    #pragma unroll
    for (int i = 0; i < 8; i++) acc[i] = (f32x4){0.f, 0.f, 0.f, 0.f};

    const char* sB = (const char*)sWT;
    #pragma unroll
    for (int ks = 0; ks < 4; ks++) {
        const int kb = ks * 32 + lq * 8;
        bf16x8 af;
        if (LAYER == 0) {
            float4 v0 = a0f[2 * ks], v1 = a0f[2 * ks + 1];
            af[0] = (short)f2bf(v0.x); af[1] = (short)f2bf(v0.y);
            af[2] = (short)f2bf(v0.z); af[3] = (short)f2bf(v0.w);
            af[4] = (short)f2bf(v1.x); af[5] = (short)f2bf(v1.y);
            af[6] = (short)f2bf(v1.z); af[7] = (short)f2bf(v1.w);
        } else {
            uint4 u = a1u[ks];
            float4 sc0 = *(const float4*)&ssl[kb];
            float4 sc1 = *(const float4*)&ssl[kb + 4];
            float4 sh0 = *(const float4*)&ssl[128 + kb];
            float4 sh1 = *(const float4*)&ssl[128 + kb + 4];
            float f0 = fmaxf(fmaf(bf_lo(u.x), sc0.x, sh0.x), 0.f);
            float f1 = fmaxf(fmaf(bf_hi(u.x), sc0.y, sh0.y), 0.f);
            float f2 = fmaxf(fmaf(bf_lo(u.y), sc0.z, sh0.z), 0.f);
            float f3 = fmaxf(fmaf(bf_hi(u.y), sc0.w, sh0.w), 0.f);
            float f4 = fmaxf(fmaf(bf_lo(u.z), sc1.x, sh1.x), 0.f);
            float f5 = fmaxf(fmaf(bf_hi(u.z), sc1.y, sh1.y), 0.f);
            float f6 = fmaxf(fmaf(bf_lo(u.w), sc1.z, sh1.z), 0.f);
            float f7 = fmaxf(fmaf(bf_hi(u.w), sc1.w, sh1.w), 0.f);
            af[0] = (short)f2bf(f0); af[1] = (short)f2bf(f1);
            af[2] = (short)f2bf(f2); af[3] = (short)f2bf(f3);
            af[4] = (short)f2bf(f4); af[5] = (short)f2bf(f5);
            af[6] = (short)f2bf(f6); af[7] = (short)f2bf(f7);
        }
        #pragma unroll
        for (int nt = 0; nt < 8; nt++) {
            const int r    = nt * 16 + lm;
            const int byte = (r * 256 + ks * 64 + lq * 16) ^ ((r & 7) << 4);
            bf16x8 bfr = *(const bf16x8*)(sB + byte);
            acc[nt] = __builtin_amdgcn_mfma_f32_16x16x32_bf16(af, bfr, acc[nt], 0, 0, 0);
        }
    }

    const int orow0 = m0 + lq * 4;
    #pragma unroll
    for (int r = 0; r < 4; r++) {
        const int orow = orow0 + r;
        if (orow < n) {
            const float s = dinv[orow];
            #pragma unroll
            for (int nt = 0; nt < 8; nt++)
                C[(size_t)orow * 128 + nt * 16 + lm] = f2bf(acc[nt][r] * s);
        }
    }
}

// -------- gather-aggregate + fused BN stats (persistent, 8-bank sums) -------
// wave per node (grid-stride); lane=(q 0..15, eg 0..3). After the butterfly
// reduce, eg==0 lanes hold the full output row: write it AND accumulate
// sum/sumsq into per-block LDS, flushed once to sums[blockIdx&7][256].
__global__ __launch_bounds__(256) void k_gather(
        const uint* __restrict__ hs, const int* __restrict__ offs,
        const int* __restrict__ deg, const int* __restrict__ csr,
        const float* __restrict__ dinv, const float* __restrict__ bias,
        uint* __restrict__ out, float* __restrict__ sums_out, int n) {
    __shared__ float bsum[128], bsq[128];
    const int t = threadIdx.x;
    if (t < 128) { bsum[t] = 0.f; bsq[t] = 0.f; }
    __syncthreads();

    const int lane = t & 63;
    const int q  = lane & 15;
    const int eg = lane >> 4;
    const int wv = (blockIdx.x * 256 + t) >> 6;
    const int nw = gridDim.x * 4;
    const uint4* hs4 = (const uint4*)hs;
    const float4 b0 = *(const float4*)&bias[q * 8];
    const float4 b1 = *(const float4*)&bias[q * 8 + 4];

    for (int node = wv; node < n; node += nw) {
        const int beg = offs[node];
        const int end = beg + deg[node];

        float acc[8];
        if (eg == 0) {                           // self loop (prescaled rows)
            uint4 sv = hs4[(size_t)node * 16 + q];
            acc[0] = bf_lo(sv.x); acc[1] = bf_hi(sv.x);
            acc[2] = bf_lo(sv.y); acc[3] = bf_hi(sv.y);
            acc[4] = bf_lo(sv.z); acc[5] = bf_hi(sv.z);
            acc[6] = bf_lo(sv.w); acc[7] = bf_hi(sv.w);
        } else {
            #pragma unroll
            for (int j = 0; j < 8; j++) acc[j] = 0.f;
        }

        for (int e = beg + eg; e < end; e += 4) {
            const int s = csr[e];
            uint4 v = hs4[(size_t)s * 16 + q];
            acc[0] += bf_lo(v.x); acc[1] += bf_hi(v.x);
            acc[2] += bf_lo(v.y); acc[3] += bf_hi(v.y);
            acc[4] += bf_lo(v.z); acc[5] += bf_hi(v.z);
            acc[6] += bf_lo(v.w); acc[7] += bf_hi(v.w);
        }

        #pragma unroll
        for (int j = 0; j < 8; j++) {
            acc[j] += __shfl_xor(acc[j], 16);
            acc[j] += __shfl_xor(acc[j], 32);
        }

        if (eg == 0) {
            const float di = dinv[node];
            float o0 = fmaf(di, acc[0], b0.x), o1 = fmaf(di, acc[1], b0.y);
            float o2 = fmaf(di, acc[2], b0.z), o3 = fmaf(di, acc[3], b0.w);
            float o4 = fmaf(di, acc[4], b1.x), o5 = fmaf(di, acc[5], b1.y);
            float o6 = fmaf(di, acc[6], b1.z), o7 = fmaf(di, acc[7], b1.w);
            uint4 o;
            o.x = (uint)f2bf(o0) | ((uint)f2bf(o1) << 16);
            o.y = (uint)f2bf(o2) | ((uint)f2bf(o3) << 16);
            o.z = (uint)f2bf(o4) | ((uint)f2bf(o5) << 16);
            o.w = (uint)f2bf(o6) | ((uint)f2bf(o7) << 16);
            ((uint4*)out)[(size_t)node * 16 + q] = o;
            const int f = q * 8;
            atomicAdd(&bsum[f + 0], o0); atomicAdd(&bsq[f + 0], o0 * o0);
            atomicAdd(&bsum[f + 1], o1); atomicAdd(&bsq[f + 1], o1 * o1);
            atomicAdd(&bsum[f + 2], o2); atomicAdd(&bsq[f + 2], o2 * o2);
            atomicAdd(&bsum[f + 3], o3); atomicAdd(&bsq[f + 3], o3 * o3);
            atomicAdd(&bsum[f + 4], o4); atomicAdd(&bsq[f + 4], o4 * o4);
            atomicAdd(&bsum[f + 5], o5); atomicAdd(&bsq[f + 5], o5 * o5);
            atomicAdd(&bsum[f + 6], o6); atomicAdd(&bsq[f + 6], o6 * o6);
            atomicAdd(&bsum[f + 7], o7); atomicAdd(&bsq[f + 7], o7 * o7);
        }
    }
    __syncthreads();
    float* sb = sums_out + (blockIdx.x & 7) * 256;
    if (t < 128)       atomicAdd(&sb[t], bsum[t]);
    else               atomicAdd(&sb[t], bsq[t - 128]);
}

// ---------------- head (BN2 derived in-block from 8 banks) ------------------
__global__ __launch_bounds__(1024) void k_final(
        const uint* __restrict__ h, const float* __restrict__ sums,
        const float* __restrict__ g, const float* __restrict__ be,
        const float* __restrict__ Wl, const float* __restrict__ bl,
        float* __restrict__ out, int n, float invn) {
    __shared__ float ssl[256];
    const int t = threadIdx.x;
    if (t < 128) {
        float s = 0.f, s2 = 0.f;
        #pragma unroll
        for (int b = 0; b < 8; b++) {
            s  += sums[b * 256 + t];
            s2 += sums[b * 256 + 128 + t];
        }
        float mean = s * invn;
        float var  = s2 * invn - mean * mean;
        float inv  = rsqrtf(var + 1e-5f);
        float sc   = g[t] * inv;
        ssl[t]       = sc;
        ssl[128 + t] = be[t] - mean * sc;
    }
    __syncthreads();
    int node = (blockIdx.x * 1024 + t) >> 6;
    int lane = t & 63;
    if (node >= n) return;
    int c = lane * 2;
    uint v = h[(size_t)node * 64 + lane];
    float a0 = fmaxf(fmaf(bf_lo(v), ssl[c],     ssl[128 + c]),     0.f);
    float a1 = fmaxf(fmaf(bf_hi(v), ssl[c + 1], ssl[128 + c + 1]), 0.f);
    float p = a0 * Wl[c] + a1 * Wl[c + 1];
    #pragma unroll
    for (int o = 32; o; o >>= 1) p += __shfl_xor(p, o);
    if (lane == 0) {
        float z = fmaxf(p + bl[0], 0.f);
        out[node] = 1.f / (1.f + expf(-z));
    }
}

extern "C" void kernel_launch(void* const* d_in, const int* in_sizes, int n_in,
                              void* d_out, int out_size, void* d_ws, size_t ws_size,
                              hipStream_t stream) {
    const float* x   = (const float*)d_in[0];
    const int*   ei  = (const int*)d_in[1];
    const float* W1  = (const float*)d_in[2];
    const float* b1  = (const float*)d_in[3];
    const float* g1  = (const float*)d_in[4];
    const float* be1 = (const float*)d_in[5];
    const float* W2  = (const float*)d_in[6];
    const float* b2  = (const float*)d_in[7];
    const float* g2  = (const float*)d_in[8];
    const float* be2 = (const float*)d_in[9];
    const float* Wl  = (const float*)d_in[10];
    const float* bl  = (const float*)d_in[11];

    const int N = in_sizes[0] / 128;
    const int E = in_sizes[1] / 2;
    const int* src  = ei;
    const int* dstp = ei + E;

    const int NBKT  = (N + 255) >> 8;
    const int CHUNK = (E + 255) / 256;         // <= 8192 for E <= 2.09M

    char* ws = (char*)d_ws;
    size_t off = 0;
    auto alloc = [&](size_t bytes) {
        void* p = ws + off;
        off += (bytes + 255) & ~(size_t)255;
        return p;
    };
    float*  dinv   = (float*) alloc((size_t)N * 4);
    int*    offs   = (int*)   alloc((size_t)N * 4);
    int*    deg    = (int*)   alloc((size_t)N * 4);
    int*    bcur   = (int*)   alloc((size_t)NBKT * 4);
    uint*   ebuf   = (uint*)  alloc((size_t)NBKT * CAP * 4);
    int*    csr    = (int*)   alloc((size_t)NBKT * CAP * 4);
    float*  sums   = (float*) alloc(16 * 256 * 4);   // [2 layers][8 banks][256]
    ushort* WT1    = (ushort*)alloc(128 * 128 * 2);
    ushort* WT2    = (ushort*)alloc(128 * 128 * 2);
    ushort* hbuf   = (ushort*)alloc((size_t)N * 128 * 2);
    ushort* abuf   = (ushort*)alloc((size_t)N * 128 * 2);

    const float invn = 1.f / (float)N;

    hipMemsetAsync(bcur, 0, (size_t)NBKT * 4, stream);

    // ---- CSR build: single-pass bucket sort + per-bucket fine sort ----
    k_sort <<<256, 256, 0, stream>>>(src, dstp, E, CHUNK, bcur, ebuf, NBKT,
                                     W1, W2, WT1, WT2, sums);
    k_bcsr <<<NBKT, 256, 0, stream>>>(ebuf, bcur, N, dinv, offs, deg, csr);

    // ---- layer 1 (stats fused into gather) ----
    k_gemm<0> <<<(N + 63) / 64, 256, 0, stream>>>(x, WT1, nullptr, nullptr, nullptr, dinv, hbuf, N, invn);
    k_gather  <<<2048, 256, 0, stream>>>((const uint*)hbuf, offs, deg, csr, dinv, b1, (uint*)abuf, sums, N);

    // ---- layer 2 (BN1+ReLU + bank-summed BN-param derivation in GEMM2) ----
    k_gemm<1> <<<(N + 63) / 64, 256, 0, stream>>>(abuf, WT2, sums, g1, be1, dinv, hbuf, N, invn);
    k_gather  <<<2048, 256, 0, stream>>>((const uint*)hbuf, offs, deg, csr, dinv, b2, (uint*)abuf, sums + 2048, N);

    // ---- head (BN2 derived from banks) ----
    k_final<<<(N + 15) / 16, 1024, 0, stream>>>((const uint*)abuf, sums + 2048, g2, be2, Wl, bl, (float*)d_out, N, invn);
}

// Round 14
// 240.850 us; speedup vs baseline: 1.7817x; 1.7817x over previous
//
#include <hip/hip_runtime.h>
#include <cstdint>
#include <cstddef>

typedef unsigned int uint;
typedef unsigned short ushort;
typedef __attribute__((ext_vector_type(8))) short bf16x8;
typedef __attribute__((ext_vector_type(4))) float f32x4;

#define CAP 4608   // padded per-bucket capacity (expected 4092, +8 sigma)

__device__ __forceinline__ ushort f2bf(float f) {          // RNE float->bf16
    uint b = __float_as_uint(f);
    return (ushort)((b + 0x7FFF + ((b >> 16) & 1)) >> 16);
}
__device__ __forceinline__ float bf_lo(uint u) { return __uint_as_float(u << 16); }
__device__ __forceinline__ float bf_hi(uint u) { return __uint_as_float(u & 0xFFFF0000u); }

// ============ CSR build, single-pass bucket sort (padded regions) ===========
__global__ __launch_bounds__(256) void k_sort(
        const int* __restrict__ src, const int* __restrict__ dst, int E, int chunk,
        int* __restrict__ bcur, uint* __restrict__ ebuf, int nbkt,
        const float* __restrict__ W1, const float* __restrict__ W2,
        ushort* __restrict__ WT1, ushort* __restrict__ WT2,
        float* __restrict__ sums) {
    __shared__ uint   ebuf_l[8192];
    __shared__ ushort bid_l[8192];
    __shared__ int    sh[256];
    __shared__ int    hist[512], histx[512], cur[512], goff[512];
    const int t   = threadIdx.x;
    const int blk = blockIdx.x;

    // fused weight prep + sums[16][256] zero (independent work)
    {
        int wi = blk * 256 + t;
        if (wi < 16384) {
            int nn = wi >> 7, k = wi & 127;
            WT1[wi] = f2bf(W1[k * 128 + nn]);
        } else if (wi < 32768) {
            int wj = wi - 16384, nn = wj >> 7, k = wj & 127;
            WT2[wj] = f2bf(W2[k * 128 + nn]);
        } else if (wi < 36864) {
            sums[wi - 32768] = 0.f;
        }
    }

    for (int b = t; b < nbkt; b += 256) hist[b] = 0;
    __syncthreads();

    const int beg = blk * chunk;
    const int end = min(beg + chunk, E);
    for (int i = beg + t; i < end; i += 256)
        atomicAdd(&hist[dst[i] >> 8], 1);
    __syncthreads();

    const int b0 = 2 * t, b1 = 2 * t + 1;
    const int c0 = (b0 < nbkt) ? hist[b0] : 0;
    const int c1 = (b1 < nbkt) ? hist[b1] : 0;
    sh[t] = c0 + c1;
    __syncthreads();
    #pragma unroll
    for (int o = 1; o < 256; o <<= 1) {
        int x = (t >= o) ? sh[t - o] : 0;
        __syncthreads();
        sh[t] += x;
        __syncthreads();
    }
    const int ex = sh[t] - (c0 + c1);
    histx[b0] = ex;       histx[b1] = ex + c0;
    cur[b0]   = ex;       cur[b1]   = ex + c0;
    __syncthreads();

    for (int b = t; b < nbkt; b += 256) {
        int h = hist[b];
        int base = (h > 0) ? atomicAdd(&bcur[b], h) : 0;
        goff[b] = b * CAP + base - histx[b];
    }
    __syncthreads();

    for (int i = beg + t; i < end; i += 256) {
        int d = dst[i];
        int s = src[i];
        int b = d >> 8;
        int p = atomicAdd(&cur[b], 1);            // LDS atomic
        ebuf_l[p] = ((uint)(d & 255) << 17) | (uint)s;
        bid_l[p]  = (ushort)b;
    }
    __syncthreads();

    const int cntE = end - beg;
    for (int i = t; i < cntE; i += 256)
        ebuf[goff[bid_l[i]] + i] = ebuf_l[i];
}

// per-bucket fine CSR: fine counts -> dinv, deg, offs(begin), grouped csr
__global__ __launch_bounds__(256) void k_bcsr(
        const uint* __restrict__ ebuf, const int* __restrict__ bcur,
        int n, float* __restrict__ dinv, int* __restrict__ offs,
        int* __restrict__ deg, int* __restrict__ csr) {
    __shared__ int fine[256], finex[256], fcur[256];
    const int b = blockIdx.x;
    const int t = threadIdx.x;
    const int ebeg = b * CAP;
    const int eend = ebeg + bcur[b];
    fine[t] = 0;
    __syncthreads();
    for (int i = ebeg + t; i < eend; i += 256)
        atomicAdd(&fine[ebuf[i] >> 17], 1);
    __syncthreads();
    const int node = b * 256 + t;
    if (node < n) {
        dinv[node] = rsqrtf((float)(fine[t] + 1));
        deg[node]  = fine[t];
    }
    int v = fine[t];
    finex[t] = v;
    __syncthreads();
    #pragma unroll
    for (int o = 1; o < 256; o <<= 1) {
        int x = (t >= o) ? finex[t - o] : 0;
        __syncthreads();
        finex[t] += x;
        __syncthreads();
    }
    const int ex = finex[t] - v;
    fcur[t] = ex;
    if (node < n) offs[node] = ebeg + ex;
    __syncthreads();
    for (int i = ebeg + t; i < eend; i += 256) {
        uint e = ebuf[i];
        int f = (int)(e >> 17);
        int p = atomicAdd(&fcur[f], 1);             // LDS atomic
        csr[ebeg + p] = (int)(e & 0x1FFFF);
    }
}

// ---------------- MFMA GEMM, WT LDS-resident (XOR-swizzled) -----------------
// C[n,128](bf16) = dinv[r] * f(A) @ W.
// LAYER 0: A fp32, f=identity. LAYER 1: A bf16, f=relu(BN(a)); BN params are
// derived in-block from the 8 replicated stat banks (fused bnparam).
template <int LAYER>
__global__ __launch_bounds__(256) void k_gemm(
        const void* __restrict__ Av, const ushort* __restrict__ WT,
        const float* __restrict__ sums, const float* __restrict__ g,
        const float* __restrict__ be, const float* __restrict__ dinv,
        ushort* __restrict__ C, int n, float invn) {
    __shared__ ushort sWT[128 * 128];   // 32 KB, rows XOR-swizzled by (row&7)<<4
    __shared__ float  ssl[256];
    const int tid  = threadIdx.x;
    const int lane = tid & 63;
    const int wid  = tid >> 6;
    const int m0   = blockIdx.x * 64 + wid * 16;
    const int lm   = lane & 15;
    const int lq   = lane >> 4;
    const int row  = m0 + lm;
    const bool rv  = row < n;

    float4 a0f[8];
    uint4  a1u[4];
    if (LAYER == 0) {
        const float* A = (const float*)Av;
        #pragma unroll
        for (int ks = 0; ks < 4; ks++) {
            const int kb = ks * 32 + lq * 8;
            if (rv) {
                a0f[2 * ks]     = *(const float4*)&A[(size_t)row * 128 + kb];
                a0f[2 * ks + 1] = *(const float4*)&A[(size_t)row * 128 + kb + 4];
            } else {
                a0f[2 * ks] = make_float4(0.f, 0.f, 0.f, 0.f);
                a0f[2 * ks + 1] = a0f[2 * ks];
            }
        }
    } else {
        const uint* A = (const uint*)Av;
        #pragma unroll
        for (int ks = 0; ks < 4; ks++) {
            const int kb = ks * 32 + lq * 8;
            a1u[ks] = rv ? *(const uint4*)&A[(size_t)row * 64 + kb / 2]
                         : make_uint4(0, 0, 0, 0);
        }
    }

    {
        const uint4* WT4 = (const uint4*)WT;
        char* sB = (char*)sWT;
        #pragma unroll
        for (int i = 0; i < 8; i++) {
            int idx  = tid + i * 256;
            uint4 v  = WT4[idx];
            int nrow = idx >> 4, j = idx & 15;
            int byte = (nrow * 256 + j * 16) ^ ((nrow & 7) << 4);
            *(uint4*)(sB + byte) = v;
        }
    }
    if (LAYER == 1 && tid < 128) {
        float s = 0.f, s2 = 0.f;
        #pragma unroll
        for (int b = 0; b < 8; b++) {
            s  += sums[b * 256 + tid];
            s2 += sums[b * 256 + 128 + tid];
        }
        float mean = s * invn;
        float var  = s2 * invn - mean * mean;
        float inv  = rsqrtf(var + 1e-5f);
        float sc   = g[tid] * inv;
        ssl[tid]       = sc;
        ssl[128 + tid] = be[tid] - mean * sc;
    }
    __syncthreads();

    f32x4 acc[8];
    #pragma unroll
    for (int i = 0; i < 8; i++) acc[i] = (f32x4){0.f, 0.f, 0.f, 0.f};

    const char* sB = (const char*)sWT;
    #pragma unroll
    for (int ks = 0; ks < 4; ks++) {
        const int kb = ks * 32 + lq * 8;
        bf16x8 af;
        if (LAYER == 0) {
            float4 v0 = a0f[2 * ks], v1 = a0f[2 * ks + 1];
            af[0] = (short)f2bf(v0.x); af[1] = (short)f2bf(v0.y);
            af[2] = (short)f2bf(v0.z); af[3] = (short)f2bf(v0.w);
            af[4] = (short)f2bf(v1.x); af[5] = (short)f2bf(v1.y);
            af[6] = (short)f2bf(v1.z); af[7] = (short)f2bf(v1.w);
        } else {
            uint4 u = a1u[ks];
            float4 sc0 = *(const float4*)&ssl[kb];
            float4 sc1 = *(const float4*)&ssl[kb + 4];
            float4 sh0 = *(const float4*)&ssl[128 + kb];
            float4 sh1 = *(const float4*)&ssl[128 + kb + 4];
            float f0 = fmaxf(fmaf(bf_lo(u.x), sc0.x, sh0.x), 0.f);
            float f1 = fmaxf(fmaf(bf_hi(u.x), sc0.y, sh0.y), 0.f);
            float f2 = fmaxf(fmaf(bf_lo(u.y), sc0.z, sh0.z), 0.f);
            float f3 = fmaxf(fmaf(bf_hi(u.y), sc0.w, sh0.w), 0.f);
            float f4 = fmaxf(fmaf(bf_lo(u.z), sc1.x, sh1.x), 0.f);
            float f5 = fmaxf(fmaf(bf_hi(u.z), sc1.y, sh1.y), 0.f);
            float f6 = fmaxf(fmaf(bf_lo(u.w), sc1.z, sh1.z), 0.f);
            float f7 = fmaxf(fmaf(bf_hi(u.w), sc1.w, sh1.w), 0.f);
            af[0] = (short)f2bf(f0); af[1] = (short)f2bf(f1);
            af[2] = (short)f2bf(f2); af[3] = (short)f2bf(f3);
            af[4] = (short)f2bf(f4); af[5] = (short)f2bf(f5);
            af[6] = (short)f2bf(f6); af[7] = (short)f2bf(f7);
        }
        #pragma unroll
        for (int nt = 0; nt < 8; nt++) {
            const int r    = nt * 16 + lm;
            const int byte = (r * 256 + ks * 64 + lq * 16) ^ ((r & 7) << 4);
            bf16x8 bfr = *(const bf16x8*)(sB + byte);
            acc[nt] = __builtin_amdgcn_mfma_f32_16x16x32_bf16(af, bfr, acc[nt], 0, 0, 0);
        }
    }

    const int orow0 = m0 + lq * 4;
    #pragma unroll
    for (int r = 0; r < 4; r++) {
        const int orow = orow0 + r;
        if (orow < n) {
            const float s = dinv[orow];
            #pragma unroll
            for (int nt = 0; nt < 8; nt++)
                C[(size_t)orow * 128 + nt * 16 + lm] = f2bf(acc[nt][r] * s);
        }
    }
}

// -------- gather-aggregate + fused BN stats (register accumulators) ---------
// Persistent grid-stride, wave per node. lane=(q 0..15, eg 0..3). eg==0 lanes
// own features q*8..q*8+7 for EVERY node they process -> accumulate sum/sumsq
// in 16 VGPRs; flush once per block at the end (plain LDS + 256 global
// atomics into 8-way replicated banks).
__global__ __launch_bounds__(256) void k_gather(
        const uint* __restrict__ hs, const int* __restrict__ offs,
        const int* __restrict__ deg, const int* __restrict__ csr,
        const float* __restrict__ dinv, const float* __restrict__ bias,
        uint* __restrict__ out, float* __restrict__ sums_out, int n) {
    __shared__ float red[4][256];
    const int t = threadIdx.x;
    const int lane = t & 63;
    const int wid  = t >> 6;
    const int q  = lane & 15;
    const int eg = lane >> 4;
    const int wv = (blockIdx.x * 256 + t) >> 6;
    const int nw = gridDim.x * 4;
    const uint4* hs4 = (const uint4*)hs;
    const float4 b0 = *(const float4*)&bias[q * 8];
    const float4 b1 = *(const float4*)&bias[q * 8 + 4];

    float rs[8], rq[8];
    #pragma unroll
    for (int j = 0; j < 8; j++) { rs[j] = 0.f; rq[j] = 0.f; }

    for (int node = wv; node < n; node += nw) {
        const int beg = offs[node];
        const int end = beg + deg[node];

        float acc[8];
        if (eg == 0) {                           // self loop (prescaled rows)
            uint4 sv = hs4[(size_t)node * 16 + q];
            acc[0] = bf_lo(sv.x); acc[1] = bf_hi(sv.x);
            acc[2] = bf_lo(sv.y); acc[3] = bf_hi(sv.y);
            acc[4] = bf_lo(sv.z); acc[5] = bf_hi(sv.z);
            acc[6] = bf_lo(sv.w); acc[7] = bf_hi(sv.w);
        } else {
            #pragma unroll
            for (int j = 0; j < 8; j++) acc[j] = 0.f;
        }

        for (int e = beg + eg; e < end; e += 4) {
            const int s = csr[e];
            uint4 v = hs4[(size_t)s * 16 + q];
            acc[0] += bf_lo(v.x); acc[1] += bf_hi(v.x);
            acc[2] += bf_lo(v.y); acc[3] += bf_hi(v.y);
            acc[4] += bf_lo(v.z); acc[5] += bf_hi(v.z);
            acc[6] += bf_lo(v.w); acc[7] += bf_hi(v.w);
        }

        #pragma unroll
        for (int j = 0; j < 8; j++) {
            acc[j] += __shfl_xor(acc[j], 16);
            acc[j] += __shfl_xor(acc[j], 32);
        }

        if (eg == 0) {
            const float di = dinv[node];
            float o0 = fmaf(di, acc[0], b0.x), o1 = fmaf(di, acc[1], b0.y);
            float o2 = fmaf(di, acc[2], b0.z), o3 = fmaf(di, acc[3], b0.w);
            float o4 = fmaf(di, acc[4], b1.x), o5 = fmaf(di, acc[5], b1.y);
            float o6 = fmaf(di, acc[6], b1.z), o7 = fmaf(di, acc[7], b1.w);
            uint4 o;
            o.x = (uint)f2bf(o0) | ((uint)f2bf(o1) << 16);
            o.y = (uint)f2bf(o2) | ((uint)f2bf(o3) << 16);
            o.z = (uint)f2bf(o4) | ((uint)f2bf(o5) << 16);
            o.w = (uint)f2bf(o6) | ((uint)f2bf(o7) << 16);
            ((uint4*)out)[(size_t)node * 16 + q] = o;
            rs[0] += o0; rq[0] = fmaf(o0, o0, rq[0]);
            rs[1] += o1; rq[1] = fmaf(o1, o1, rq[1]);
            rs[2] += o2; rq[2] = fmaf(o2, o2, rq[2]);
            rs[3] += o3; rq[3] = fmaf(o3, o3, rq[3]);
            rs[4] += o4; rq[4] = fmaf(o4, o4, rq[4]);
            rs[5] += o5; rq[5] = fmaf(o5, o5, rq[5]);
            rs[6] += o6; rq[6] = fmaf(o6, o6, rq[6]);
            rs[7] += o7; rq[7] = fmaf(o7, o7, rq[7]);
        }
    }

    // flush: plain LDS stores (eg==0 lanes cover all 128 features per wave)
    if (eg == 0) {
        #pragma unroll
        for (int j = 0; j < 8; j++) {
            red[wid][q * 8 + j]       = rs[j];
            red[wid][128 + q * 8 + j] = rq[j];
        }
    }
    __syncthreads();
    float v = red[0][t] + red[1][t] + red[2][t] + red[3][t];
    atomicAdd(&sums_out[(blockIdx.x & 7) * 256 + t], v);
}

// ---------------- head (BN2 derived in-block from 8 banks) ------------------
__global__ __launch_bounds__(1024) void k_final(
        const uint* __restrict__ h, const float* __restrict__ sums,
        const float* __restrict__ g, const float* __restrict__ be,
        const float* __restrict__ Wl, const float* __restrict__ bl,
        float* __restrict__ out, int n, float invn) {
    __shared__ float ssl[256];
    const int t = threadIdx.x;
    if (t < 128) {
        float s = 0.f, s2 = 0.f;
        #pragma unroll
        for (int b = 0; b < 8; b++) {
            s  += sums[b * 256 + t];
            s2 += sums[b * 256 + 128 + t];
        }
        float mean = s * invn;
        float var  = s2 * invn - mean * mean;
        float inv  = rsqrtf(var + 1e-5f);
        float sc   = g[t] * inv;
        ssl[t]       = sc;
        ssl[128 + t] = be[t] - mean * sc;
    }
    __syncthreads();
    int node = (blockIdx.x * 1024 + t) >> 6;
    int lane = t & 63;
    if (node >= n) return;
    int c = lane * 2;
    uint v = h[(size_t)node * 64 + lane];
    float a0 = fmaxf(fmaf(bf_lo(v), ssl[c],     ssl[128 + c]),     0.f);
    float a1 = fmaxf(fmaf(bf_hi(v), ssl[c + 1], ssl[128 + c + 1]), 0.f);
    float p = a0 * Wl[c] + a1 * Wl[c + 1];
    #pragma unroll
    for (int o = 32; o; o >>= 1) p += __shfl_xor(p, o);
    if (lane == 0) {
        float z = fmaxf(p + bl[0], 0.f);
        out[node] = 1.f / (1.f + expf(-z));
    }
}

extern "C" void kernel_launch(void* const* d_in, const int* in_sizes, int n_in,
                              void* d_out, int out_size, void* d_ws, size_t ws_size,
                              hipStream_t stream) {
    const float* x   = (const float*)d_in[0];
    const int*   ei  = (const int*)d_in[1];
    const float* W1  = (const float*)d_in[2];
    const float* b1  = (const float*)d_in[3];
    const float* g1  = (const float*)d_in[4];
    const float* be1 = (const float*)d_in[5];
    const float* W2  = (const float*)d_in[6];
    const float* b2  = (const float*)d_in[7];
    const float* g2  = (const float*)d_in[8];
    const float* be2 = (const float*)d_in[9];
    const float* Wl  = (const float*)d_in[10];
    const float* bl  = (const float*)d_in[11];

    const int N = in_sizes[0] / 128;
    const int E = in_sizes[1] / 2;
    const int* src  = ei;
    const int* dstp = ei + E;

    const int NBKT  = (N + 255) >> 8;
    const int CHUNK = (E + 255) / 256;         // <= 8192 for E <= 2.09M

    char* ws = (char*)d_ws;
    size_t off = 0;
    auto alloc = [&](size_t bytes) {
        void* p = ws + off;
        off += (bytes + 255) & ~(size_t)255;
        return p;
    };
    float*  dinv   = (float*) alloc((size_t)N * 4);
    int*    offs   = (int*)   alloc((size_t)N * 4);
    int*    deg    = (int*)   alloc((size_t)N * 4);
    int*    bcur   = (int*)   alloc((size_t)NBKT * 4);
    uint*   ebuf   = (uint*)  alloc((size_t)NBKT * CAP * 4);
    int*    csr    = (int*)   alloc((size_t)NBKT * CAP * 4);
    float*  sums   = (float*) alloc(16 * 256 * 4);   // [2 layers][8 banks][256]
    ushort* WT1    = (ushort*)alloc(128 * 128 * 2);
    ushort* WT2    = (ushort*)alloc(128 * 128 * 2);
    ushort* hbuf   = (ushort*)alloc((size_t)N * 128 * 2);
    ushort* abuf   = (ushort*)alloc((size_t)N * 128 * 2);

    const float invn = 1.f / (float)N;

    hipMemsetAsync(bcur, 0, (size_t)NBKT * 4, stream);

    // ---- CSR build: single-pass bucket sort + per-bucket fine sort ----
    k_sort <<<256, 256, 0, stream>>>(src, dstp, E, CHUNK, bcur, ebuf, NBKT,
                                     W1, W2, WT1, WT2, sums);
    k_bcsr <<<NBKT, 256, 0, stream>>>(ebuf, bcur, N, dinv, offs, deg, csr);

    // ---- layer 1 (stats fused into gather, register accumulators) ----
    k_gemm<0> <<<(N + 63) / 64, 256, 0, stream>>>(x, WT1, nullptr, nullptr, nullptr, dinv, hbuf, N, invn);
    k_gather  <<<2048, 256, 0, stream>>>((const uint*)hbuf, offs, deg, csr, dinv, b1, (uint*)abuf, sums, N);

    // ---- layer 2 (BN1+ReLU + bank-summed BN-param derivation in GEMM2) ----
    k_gemm<1> <<<(N + 63) / 64, 256, 0, stream>>>(abuf, WT2, sums, g1, be1, dinv, hbuf, N, invn);
    k_gather  <<<2048, 256, 0, stream>>>((const uint*)hbuf, offs, deg, csr, dinv, b2, (uint*)abuf, sums + 2048, N);

    // ---- head (BN2 derived from banks) ----
    k_final<<<(N + 15) / 16, 1024, 0, stream>>>((const uint*)abuf, sums + 2048, g2, be2, Wl, bl, (float*)d_out, N, invn);
}